// Round 1
// 169.916 us; speedup vs baseline: 1.1500x; 1.1500x over previous
//
#include <hip/hip_runtime.h>
#include <math.h>

typedef __attribute__((ext_vector_type(8))) short short8;
typedef __attribute__((ext_vector_type(4))) float floatx4;
typedef __attribute__((ext_vector_type(4))) unsigned int uintx4;

#define NB    4
#define CIN   64
#define COUT  128
#define IMH   128
#define IMW   256
#define KTOT  576
#define NPIX  (IMH * IMW)
#define PXT   128
#define NDPB  (PXT * 9)        // 1152 descriptors (px x tap), shared by all chunks
#define ROWS  4                // staged rows r-2..r+1 (|new_r - r| < 1.415 proven)
#define CST   12               // f32 words per staged column (8 ch + 4 pad, 48B)
#define NCOL  257              // cols 0..255 + zero col 256
#define RST   (NCOL * CST)     // 3084 words per staged row
#define SLSTR 104              // u16 per px in Sl (96 K + 8 pad; 52w = 20 mod 32)
#define KCH   96               // padded K per chunk (72 real + 24 zeros)

__device__ __forceinline__ unsigned short f2bf(float f) {
  union { float f; unsigned u; } v; v.f = f;
  return (unsigned short)((v.u + 0x7FFFu + ((v.u >> 16) & 1u)) >> 16);
}
__device__ __forceinline__ unsigned cvtpk(float lo, float hi) {
  unsigned r;
  asm("v_cvt_pk_bf16_f32 %0, %1, %2" : "=v"(r) : "v"(lo), "v"(hi));
  return r;
}

// ---- kernel 1: weight fp32 [co][ci*9+k] -> bf16, K' = chunk*96 + k*8 + (ci&7) ----
// (8 chunks of 8ch x 9taps, zero-padded 72->96 so each chunk is 3 x K32 MFMA steps)
__global__ __launch_bounds__(256) void prep_w_kernel(const float* __restrict__ w,
                                                     unsigned short* __restrict__ wbf) {
  int idx = blockIdx.x * 256 + threadIdx.x;
  if (idx >= COUT * 8 * KCH) return;
  int co = idx / (8 * KCH);
  int K2 = idx - co * (8 * KCH);
  int cb = K2 / KCH, kk = K2 - cb * KCH;
  unsigned short v = 0;
  if (kk < 72) {
    int t = kk >> 3, chl = kk & 7;
    int ci = cb * 8 + chl;
    v = f2bf(w[co * KTOT + ci * 9 + t]);
  }
  wbf[(K2 >> 3) * (COUT * 8) + co * 8 + (K2 & 7)] = v;
}

// ---- kernel 2: fused desc-gen + ch-interleaved f32 staging + b128 gather + MFMA ----
__global__ __launch_bounds__(512, 4) void sphconv_kernel(
    const float* __restrict__ x, const unsigned short* __restrict__ wbf,
    const float* __restrict__ bias, float* __restrict__ out) {
  __shared__ __align__(16) float stg[ROWS * RST];             // 49,344 B
  __shared__ __align__(16) unsigned short Sl[PXT * SLSTR];    // 26,624 B

  const int tid  = threadIdx.x;
  const int lane = tid & 63;
  const int wv   = tid >> 6;
  // XCD-chunked swizzle: 32 consecutive (ct,r) blocks per XCD -> L2 row reuse
  const int lin = blockIdx.x + 2 * blockIdx.y;   // dispatch-linear 0..255
  const int sw  = (lin & 7) * 32 + (lin >> 3);   // bijective (256 = 8*32)
  const int ct  = sw >> 7;
  const int r   = sw & 127;
  const int n   = blockIdx.z;
  const int c0  = ct * PXT;
  const int co_base = (wv & 1) * 64;
  const int px_base = (wv >> 1) * 32;
  const int rlo  = min(max(r - 2, 0), IMH - ROWS);
  const int ch   = tid & 7;       // staging role: channel-in-chunk
  const int colg = tid >> 3;      // staging role: col-group 0..63

  const float* xn = x + (size_t)n * CIN * NPIX;

  // ---- prologue: issue chunk-0 staging loads (land during f64 desc-gen) ----
  floatx4 pre[ROWS];
  {
    const float* src = xn + (size_t)ch * NPIX + (size_t)rlo * IMW + colg * 4;
    #pragma unroll
    for (int row = 0; row < ROWS; row++)
      pre[row] = *(const floatx4*)(src + row * IMW);
  }

  // ---- phase 0: descriptors (f64 trig, once; reused by all 8 chunks) ----
  int opk[3] = {0, 0, 0}, slw[3] = {0, 0, 0};
  float wq0[3] = {0.f, 0.f, 0.f}, wq1[3] = {0.f, 0.f, 0.f};
  float wq2[3] = {0.f, 0.f, 0.f}, wq3[3] = {0.f, 0.f, 0.f};
  {
    const double pi = 3.14159265358979323846;
    double dphi = pi / IMH;
    double dth  = 2.0 * pi / IMW;
    double t  = tan(dth);
    double p  = tan(dphi);
    double sp = p / cos(dth);
    double phi  = -(((double)r + 0.5) / IMH * pi - pi * 0.5);
    double sphi = sin(phi), cphi = cos(phi);
    #pragma unroll
    for (int dd = 0; dd < 3; dd++) {
      if (dd < 2 || tid < NDPB - 1024) {
        int d  = tid + dd * 512;
        int px = d & (PXT - 1), k = d >> 7;   // wave-uniform k
        int c  = c0 + px;
        int i = k / 3, j = k % 3;
        double theta = ((double)c + 0.5) / IMW * (2.0 * pi) - pi;
        double new_r, new_c;
        if (k == 4) {
          new_r = (double)r; new_c = (double)c;
        } else {
          double X = (j == 0) ? -t : ((j == 2) ? t : 0.0);
          double Y = 0.0;
          if (i == 0)      Y = (j == 1) ?  p :  sp;
          else if (i == 2) Y = (j == 1) ? -p : -sp;
          double rho = sqrt(X * X + Y * Y);
          double v   = atan(rho);
          double sv = sin(v), cv = cos(v);
          double arg = cv * sphi + Y * sv * cphi / rho;
          arg = fmin(1.0, fmax(-1.0, arg));
          double new_phi = asin(arg);
          double denom = rho * cphi * cv - Y * sphi * sv;
          double new_theta = theta + atan(X * sv / denom);
          new_r = (-new_phi + pi * 0.5) * IMH / pi - 0.5;
          new_c = (new_theta + pi) * IMW / (2.0 * pi) - 0.5;
          new_c = fmod(new_c + (double)IMW, (double)IMW);
        }
        float gx = (float)(new_c * 2.0 / IMW - 1.0);
        float gy = (float)(new_r * 2.0 / IMH - 1.0);
        float ix = ((gx + 1.0f) * (float)IMW - 1.0f) * 0.5f;
        float iy = ((gy + 1.0f) * (float)IMH - 1.0f) * 0.5f;
        float fx = floorf(ix), fy = floorf(iy);
        int x0 = (int)fx, y0 = (int)fy;
        float wx1 = ix - fx, wy1 = iy - fy;
        float wx0 = 1.0f - wx1, wy0 = 1.0f - wy1;
        int x1 = x0 + 1, y1 = y0 + 1;
        bool vy0 = (y0 >= 0) & (y0 <= IMH - 1);
        bool vy1 = (y1 >= 0) & (y1 <= IMH - 1);
        int y0c = min(max(y0, 0), IMH - 1), y1c = min(max(y1, 0), IMH - 1);
        int x0c = max(x0, 0);
        float w_lo = (x0 >= 0) ? wx0 : wx1;
        float w_hi = (x0 >= 0) ? ((x1 <= IMW - 1) ? wx1 : 0.0f) : 0.0f;
        float wy0m = vy0 ? wy0 : 0.0f, wy1m = vy1 ? wy1 : 0.0f;
        int rt = min(max(y0c - rlo, 0), ROWS - 1);    // proven in [0,3]; clamp = safety
        int rb = min(max(y1c - rlo, 0), ROWS - 1);
        opk[dd] = (rt * RST + x0c * CST) | ((rb * RST + x0c * CST) << 16); // <=12312 each
        wq0[dd] = wy0m * w_lo; wq1[dd] = wy0m * w_hi;
        wq2[dd] = wy1m * w_lo; wq3[dd] = wy1m * w_hi;
        slw[dd] = px * (SLSTR / 2) + k * 4;           // u32-word offset into Sl
      }
    }
  }

  // ---- write chunk-0 stage; zero col-256 and Sl K-pad (stay zero afterwards) ----
  {
    float* dch = &stg[(colg * 4) * CST + ch];
    #pragma unroll
    for (int row = 0; row < ROWS; row++) {
      floatx4 v = pre[row];
      float* dr = dch + row * RST;
      dr[0] = v.x; dr[CST] = v.y; dr[2 * CST] = v.z; dr[3 * CST] = v.w;
    }
  }
  if (tid < 32) stg[(tid >> 3) * RST + 256 * CST + (tid & 7)] = 0.0f;
  #pragma unroll
  for (int z = 0; z < 3; z++) {                 // 128 px * 12 pad-words = 3*512
    int q = tid + z * 512;
    int px = q / 12;
    ((unsigned int*)Sl)[px * 52 + 36 + (q - px * 12)] = 0u;
  }

  floatx4 acc[4][2];
  #pragma unroll
  for (int mt = 0; mt < 4; mt++)
    #pragma unroll
    for (int nt = 0; nt < 2; nt++)
      acc[mt][nt] = (floatx4){0.f, 0.f, 0.f, 0.f};

  __syncthreads();

  #pragma unroll 1
  for (int cb = 0; cb < 8; cb++) {
    // ---- gather: all 8 channels per descriptor, b128 reads + one b128 write ----
    #pragma unroll
    for (int dd = 0; dd < 3; dd++) {
      if (dd < 2 || tid < NDPB - 1024) {
        unsigned op = (unsigned)opk[dd];
        const float* pt = &stg[op & 0xFFFFu];
        const float* pb = &stg[op >> 16];
        floatx4 t0  = *(const floatx4*)(pt);
        floatx4 t0h = *(const floatx4*)(pt + 4);
        floatx4 t1  = *(const floatx4*)(pt + CST);
        floatx4 t1h = *(const floatx4*)(pt + CST + 4);
        floatx4 b0  = *(const floatx4*)(pb);
        floatx4 b0h = *(const floatx4*)(pb + 4);
        floatx4 b1  = *(const floatx4*)(pb + CST);
        floatx4 b1h = *(const floatx4*)(pb + CST + 4);
        float w0 = wq0[dd], w1 = wq1[dd], w2 = wq2[dd], w3 = wq3[dd];
        floatx4 slo = t0 * w0 + t1 * w1 + b0 * w2 + b1 * w3;
        floatx4 shi = t0h * w0 + t1h * w1 + b0h * w2 + b1h * w3;
        uintx4 U;
        U.x = cvtpk(slo.x, slo.y); U.y = cvtpk(slo.z, slo.w);
        U.z = cvtpk(shi.x, shi.y); U.w = cvtpk(shi.z, shi.w);
        *(uintx4*)((unsigned int*)Sl + slw[dd]) = U;
      }
    }
    __syncthreads();            // Sl ready; stg free (gather reads done)
    // ---- stage chunk cb+1: overlaps MFMA below (stg vs Sl, no conflict) ----
    if (cb < 7) {
      const float* src = xn + (size_t)((cb + 1) * 8 + ch) * NPIX + (size_t)rlo * IMW + colg * 4;
      float* dch = &stg[(colg * 4) * CST + ch];
      #pragma unroll
      for (int row = 0; row < ROWS; row++) {
        floatx4 v = *(const floatx4*)(src + row * IMW);
        float* dr = dch + row * RST;
        dr[0] = v.x; dr[CST] = v.y; dr[2 * CST] = v.z; dr[3 * CST] = v.w;
      }
    }
    // ---- MFMA: 3 x K32 steps over this chunk's 96 padded K ----
    #pragma unroll
    for (int ks = 0; ks < 3; ks++) {
      const unsigned short* arow =
          wbf + (size_t)((cb * 12 + ks * 4 + (lane >> 4)) * COUT + co_base + (lane & 15)) * 8;
      #pragma unroll
      for (int nt = 0; nt < 2; nt++) {
        short8 b = *(const short8*)&Sl[(px_base + nt * 16 + (lane & 15)) * SLSTR
                                       + ks * 32 + (lane >> 4) * 8];
        #pragma unroll
        for (int mt = 0; mt < 4; mt++) {
          short8 a = *(const short8*)(arow + mt * 16 * 8);
          acc[mt][nt] = __builtin_amdgcn_mfma_f32_16x16x32_bf16(a, b, acc[mt][nt], 0, 0, 0);
        }
      }
    }
    __syncthreads();            // Sl free for next gather; stg(cb+1) ready
  }

  // ---- epilogue: D row = co, col = px ----
  #pragma unroll
  for (int mt = 0; mt < 4; mt++)
    #pragma unroll
    for (int nt = 0; nt < 2; nt++)
      #pragma unroll
      for (int rg = 0; rg < 4; rg++) {
        const int co = co_base + mt * 16 + (lane >> 4) * 4 + rg;
        const int cc = c0 + px_base + nt * 16 + (lane & 15);
        out[(((size_t)n * COUT + co) * IMH + r) * IMW + cc] = acc[mt][nt][rg] + bias[co];
      }
}

extern "C" void kernel_launch(void* const* d_in, const int* in_sizes, int n_in,
                              void* d_out, int out_size, void* d_ws, size_t ws_size,
                              hipStream_t stream) {
  const float* x    = (const float*)d_in[0];
  const float* w    = (const float*)d_in[1];
  const float* bias = (const float*)d_in[2];
  float* out = (float*)d_out;
  unsigned short* wbf = (unsigned short*)d_ws;   // 192 KB workspace
  (void)in_sizes; (void)n_in; (void)out_size; (void)ws_size;

  hipLaunchKernelGGL(prep_w_kernel, dim3((COUT * 8 * KCH + 255) / 256), dim3(256), 0, stream, w, wbf);
  hipLaunchKernelGGL(sphconv_kernel, dim3(IMW / PXT, IMH, NB), dim3(512), 0, stream,
                     x, wbf, bias, out);
}